// Round 6
// baseline (327.297 us; speedup 1.0000x reference)
//
#include <hip/hip_runtime.h>

typedef _Float16 f16;
typedef f16 f16x4 __attribute__((ext_vector_type(4)));
typedef f16 f16x8 __attribute__((ext_vector_type(8)));
typedef float f32x4 __attribute__((ext_vector_type(4)));

#define NB 4
#define NS 2048
#define ND 1024
#define NH 16
#define NDH 64

__device__ __forceinline__ void gl2lds16(const void* g, void* l) {
  __builtin_amdgcn_global_load_lds(
      (const __attribute__((address_space(1))) unsigned int*)g,
      (__attribute__((address_space(3))) unsigned int*)l, 16, 0, 0);
}

__device__ __forceinline__ float fast_exp2(float x) {
  return __builtin_amdgcn_exp2f(x);  // v_exp_f32
}

// ---------------- fp32 -> f16 conversion ----------------
__global__ __launch_bounds__(256) void cvt_kernel(const float* __restrict__ src,
                                                  f16* __restrict__ dst, int n4) {
  int i = blockIdx.x * 256 + threadIdx.x;
  if (i >= n4) return;
  float4 v = ((const float4*)src)[i];
  f16x4 h = {(f16)v.x, (f16)v.y, (f16)v.z, (f16)v.w};
  ((f16x4*)dst)[i] = h;
}

// ---------------- fused QKV projection GEMM ----------------
// QF/KF layout (row-major per 16-row tile, 128B rows):
//   QF[bh][st][r16][dh] = M[s=st*16+r16][dh],  dh 0..63 contiguous
//   -> one 16B load gives the K=32 MFMA A/B-frag (k=quad*8+j).
//   Q is pre-scaled by 1/8*log2(e) (softmax fold).
// VF layout (K=16 PV B-frag order):
//   VF[bh][kt][lane][dt*4+jj] = V[key=kt*16+(lane>>4)*4+jj][dh=dt*16+(lane&15)]
__global__ __launch_bounds__(256) void qkv_gemm(
    const f16* __restrict__ Xh, const f16* __restrict__ Wh,
    const float* __restrict__ bq, const float* __restrict__ bk,
    const float* __restrict__ bv,
    f16* __restrict__ QF, f16* __restrict__ KF, f16* __restrict__ VF) {
  __shared__ f16 Ah[128 * 32];
  __shared__ f16 Bh[128 * 32];
  const int t = threadIdx.x;
  const int tileM = blockIdx.x * 128;
  const int nGlob = blockIdx.y * 128;
  const int mat = nGlob >> 10;
  const int col0 = nGlob & 1023;
  const int wave = t >> 6, lane = t & 63;
  const int mOff = (wave & 1) * 64, nOff = (wave >> 1) * 64;
  const int lr = lane & 15, quad = lane >> 4;

  f32x4 acc[4][4];
#pragma unroll
  for (int i = 0; i < 4; i++)
#pragma unroll
    for (int j = 0; j < 4; j++) acc[i][j] = f32x4{0.f, 0.f, 0.f, 0.f};

  const int srow = t >> 2, schunk = (t & 3) * 8;
  const f16* ag = Xh + (size_t)(tileM + srow) * ND + schunk;
  const f16* bg = Wh + (size_t)mat * ND * ND + (size_t)(col0 + srow) * ND + schunk;
  const bool qk = (mat < 2);

  for (int kk = 0; kk < ND; kk += 32) {
    __syncthreads();
    gl2lds16(ag + kk, Ah + t * 8);
    gl2lds16(ag + (size_t)64 * ND + kk, Ah + 2048 + t * 8);
    gl2lds16(bg + kk, Bh + t * 8);
    gl2lds16(bg + (size_t)64 * ND + kk, Bh + 2048 + t * 8);
    __syncthreads();
    f16x8 af[4], bf[4];
#pragma unroll
    for (int i = 0; i < 4; i++)
      af[i] = *(const f16x8*)(Ah + (mOff + i * 16 + lr) * 32 + quad * 8);
#pragma unroll
    for (int j = 0; j < 4; j++)
      bf[j] = *(const f16x8*)(Bh + (nOff + j * 16 + lr) * 32 + quad * 8);
    if (qk) {
#pragma unroll
      for (int i = 0; i < 4; i++)
#pragma unroll
        for (int j = 0; j < 4; j++)
          acc[i][j] = __builtin_amdgcn_mfma_f32_16x16x32_f16(bf[j], af[i], acc[i][j], 0, 0, 0);
    } else {
#pragma unroll
      for (int i = 0; i < 4; i++)
#pragma unroll
        for (int j = 0; j < 4; j++)
          acc[i][j] = __builtin_amdgcn_mfma_f32_16x16x32_f16(af[i], bf[j], acc[i][j], 0, 0, 0);
    }
  }

  if (qk) {
    // acc[i][j][r] = C[dh_n = col0+nOff+j*16+quad*4+r][s = tileM+mOff+i*16+lr]
    const float* bias = (mat == 0) ? bq : bk;
    f16* dst = (mat == 0) ? QF : KF;
    const float sc = (mat == 0) ? 0.18033688f : 1.0f;  // 1/8*log2(e) folded into Q
#pragma unroll
    for (int j = 0; j < 4; j++) {
      int n0 = col0 + nOff + j * 16;
      int h = n0 >> 6;
      int dloc = (n0 & 63) + quad * 4;
      float4 bb = *(const float4*)(bias + n0 + quad * 4);
#pragma unroll
      for (int i = 0; i < 4; i++) {
        int sF = tileM + mOff + i * 16;
        int b = sF >> 11, st = (sF & 2047) >> 4;
        int bh = b * NH + h;
        f16x4 v;
#pragma unroll
        for (int r = 0; r < 4; r++) v[r] = (f16)((acc[i][j][r] + (&bb.x)[r]) * sc);
        *(f16x4*)(dst + (size_t)(bh * 128 + st) * 1024 + lr * 64 + dloc) = v;
      }
    }
  } else {
    // acc[i][j][r] = C[key = tileM+mOff+i*16+quad*4+r][dh_n = col0+nOff+j*16+lr]
#pragma unroll
    for (int j = 0; j < 4; j++) {
      int n = col0 + nOff + j * 16 + lr;
      int h = n >> 6, dt = (n >> 4) & 3;
      float bb = bv[n];
#pragma unroll
      for (int i = 0; i < 4; i++) {
        int sF = tileM + mOff + i * 16;
        int b = sF >> 11, kt = (sF & 2047) >> 4;
        int bh = b * NH + h;
        f16x4 v;
#pragma unroll
        for (int r = 0; r < 4; r++) v[r] = (f16)(acc[i][j][r] + bb);
        *(f16x4*)(VF + ((size_t)(bh * 128 + kt) * 64 + lane) * 16 + dt * 4) = v;
      }
    }
  }
}

// ---------------- flash attention: zero LDS, zero barriers ----------------
// grid (16,64), 256 thr = 4 waves, wave owns 32 q (2 qtiles).
// S^T = K.Q^T via mfma_16x16x32 (K,Q row-major frags); exp in registers;
// P (C-layout) == A-frag for K=16 PV. Two-bank prefetch, no reg rotation.
__global__ __launch_bounds__(256) void attn_kernel(
    const f16* __restrict__ QF, const f16* __restrict__ KF,
    const f16* __restrict__ VF, float* __restrict__ out) {
  const int t = threadIdx.x, wave = t >> 6, lane = t & 63;
  const int lr = lane & 15, quad = lane >> 4;
  const int qb = blockIdx.x, bh = blockIdx.y;
  const int bb = bh >> 4, hh = bh & 15;
  const size_t bhOff = (size_t)bh * 131072;
  const f16* Qp = QF + bhOff + (size_t)lr * 64 + quad * 8;
  const f16* Kp = KF + bhOff + (size_t)lr * 64 + quad * 8;
  const f16* Vp = VF + bhOff + (size_t)lane * 16;
  const int st0 = qb * 8 + wave * 2;

  // Q B-frags for K=32 (n=q=lane&15, k=dh=quad*8+j (+32 for ks=1)); pre-scaled
  f16x8 qf[2][2];
#pragma unroll
  for (int qt = 0; qt < 2; qt++) {
    qf[qt][0] = *(const f16x8*)(Qp + (size_t)(st0 + qt) * 1024);
    qf[qt][1] = *(const f16x8*)(Qp + (size_t)(st0 + qt) * 1024 + 32);
  }

  f32x4 o[2][4];
#pragma unroll
  for (int qt = 0; qt < 2; qt++)
#pragma unroll
    for (int dt = 0; dt < 4; dt++) o[qt][dt] = f32x4{0.f, 0.f, 0.f, 0.f};
  float lsum[2] = {0.f, 0.f};

  auto compute = [&](f16x8 k0, f16x8 k1, f16x8 v0, f16x8 v1) {
    // S^T[key][q]: A = K-frag (m=key), B = Q-frag (n=q), K-dim = dh = 64
    f32x4 s[2] = {f32x4{0.f, 0.f, 0.f, 0.f}, f32x4{0.f, 0.f, 0.f, 0.f}};
#pragma unroll
    for (int qt = 0; qt < 2; qt++) {
      s[qt] = __builtin_amdgcn_mfma_f32_16x16x32_f16(k0, qf[qt][0], s[qt], 0, 0, 0);
      s[qt] = __builtin_amdgcn_mfma_f32_16x16x32_f16(k1, qf[qt][1], s[qt], 0, 0, 0);
    }
    // p = exp2(s) (scale pre-folded into Q); stays in regs as PV A-frag
    f16x4 p[2];
#pragma unroll
    for (int qt = 0; qt < 2; qt++) {
      float e0 = fast_exp2(s[qt][0]);
      float e1 = fast_exp2(s[qt][1]);
      float e2 = fast_exp2(s[qt][2]);
      float e3 = fast_exp2(s[qt][3]);
      lsum[qt] += (e0 + e1) + (e2 + e3);
      p[qt] = f16x4{(f16)e0, (f16)e1, (f16)e2, (f16)e3};
    }
    f16x4 vv[4];
    vv[0] = __builtin_shufflevector(v0, v0, 0, 1, 2, 3);
    vv[1] = __builtin_shufflevector(v0, v0, 4, 5, 6, 7);
    vv[2] = __builtin_shufflevector(v1, v1, 0, 1, 2, 3);
    vv[3] = __builtin_shufflevector(v1, v1, 4, 5, 6, 7);
#pragma unroll
    for (int dt = 0; dt < 4; dt++) {
      o[0][dt] = __builtin_amdgcn_mfma_f32_16x16x16f16(p[0], vv[dt], o[0][dt], 0, 0, 0);
      o[1][dt] = __builtin_amdgcn_mfma_f32_16x16x16f16(p[1], vv[dt], o[1][dt], 0, 0, 0);
    }
  };

  // two-bank software pipeline: prefetch B, compute A, prefetch A, compute B
  f16x8 kA0 = *(const f16x8*)(Kp);
  f16x8 kA1 = *(const f16x8*)(Kp + 32);
  f16x8 vA0 = *(const f16x8*)(Vp);
  f16x8 vA1 = *(const f16x8*)(Vp + 8);

  for (int kt = 0; kt < 128; kt += 2) {
    f16x8 kB0 = *(const f16x8*)(Kp + (size_t)(kt + 1) * 1024);
    f16x8 kB1 = *(const f16x8*)(Kp + (size_t)(kt + 1) * 1024 + 32);
    f16x8 vB0 = *(const f16x8*)(Vp + (size_t)(kt + 1) * 1024);
    f16x8 vB1 = *(const f16x8*)(Vp + (size_t)(kt + 1) * 1024 + 8);
    compute(kA0, kA1, vA0, vA1);
    const int kn = (kt + 2) & 127;  // branchless wrap keeps address in-bounds
    kA0 = *(const f16x8*)(Kp + (size_t)kn * 1024);
    kA1 = *(const f16x8*)(Kp + (size_t)kn * 1024 + 32);
    vA0 = *(const f16x8*)(Vp + (size_t)kn * 1024);
    vA1 = *(const f16x8*)(Vp + (size_t)kn * 1024 + 8);
    compute(kB0, kB1, vB0, vB1);
  }

  // lsum: lane holds q=lr partial over its key subset -> reduce across quads
#pragma unroll
  for (int qt = 0; qt < 2; qt++) {
    lsum[qt] += __shfl_xor(lsum[qt], 16);
    lsum[qt] += __shfl_xor(lsum[qt], 32);
  }
  // O C-layout: lane holds q=quad*4+r, dh=dt*16+lr
#pragma unroll
  for (int qt = 0; qt < 2; qt++) {
#pragma unroll
    for (int r = 0; r < 4; r++) {
      float inv = 1.0f / __shfl(lsum[qt], quad * 4 + r);
      int q = qb * 128 + wave * 32 + qt * 16 + quad * 4 + r;
#pragma unroll
      for (int dt = 0; dt < 4; dt++)
        out[((size_t)bb * NS + q) * ND + hh * 64 + dt * 16 + lr] = o[qt][dt][r] * inv;
    }
  }
}

extern "C" void kernel_launch(void* const* d_in, const int* in_sizes, int n_in,
                              void* d_out, int out_size, void* d_ws, size_t ws_size,
                              hipStream_t stream) {
  const float* X  = (const float*)d_in[0];
  const float* Wq = (const float*)d_in[1];
  const float* bq = (const float*)d_in[2];
  const float* Wk = (const float*)d_in[3];
  const float* bk = (const float*)d_in[4];
  const float* Wv = (const float*)d_in[5];
  const float* bv = (const float*)d_in[6];
  float* out = (float*)d_out;

  // ws: Xh 16MB | Wh 6MB | QF 16MB | KF 16MB | VF 16MB = 70MB
  f16* Xh = (f16*)d_ws;
  f16* Wh = (f16*)((char*)d_ws + (size_t)(16u << 20));
  f16* QF = (f16*)((char*)d_ws + (size_t)(22u << 20));
  f16* KF = (f16*)((char*)d_ws + (size_t)(38u << 20));
  f16* VF = (f16*)((char*)d_ws + (size_t)(54u << 20));

  cvt_kernel<<<8192, 256, 0, stream>>>(X, Xh, 2097152);
  cvt_kernel<<<1024, 256, 0, stream>>>(Wq, Wh, 262144);
  cvt_kernel<<<1024, 256, 0, stream>>>(Wk, Wh + (1u << 20), 262144);
  cvt_kernel<<<1024, 256, 0, stream>>>(Wv, Wh + (2u << 20), 262144);
  qkv_gemm<<<dim3(64, 24), 256, 0, stream>>>(Xh, Wh, bq, bk, bv, QF, KF, VF);
  attn_kernel<<<dim3(16, 64), 256, 0, stream>>>(QF, KF, VF, out);
}

// Round 8
// 287.255 us; speedup vs baseline: 1.1394x; 1.1394x over previous
//
#include <hip/hip_runtime.h>

typedef _Float16 f16;
typedef f16 f16x2 __attribute__((ext_vector_type(2)));
typedef f16 f16x4 __attribute__((ext_vector_type(4)));
typedef f16 f16x8 __attribute__((ext_vector_type(8)));
typedef float f32x4 __attribute__((ext_vector_type(4)));

#define NB 4
#define NS 2048
#define ND 1024
#define NH 16
#define NDH 64

__device__ __forceinline__ void gl2lds16(const void* g, void* l) {
  __builtin_amdgcn_global_load_lds(
      (const __attribute__((address_space(1))) unsigned int*)g,
      (__attribute__((address_space(3))) unsigned int*)l, 16, 0, 0);
}

__device__ __forceinline__ float fast_exp2(float x) {
  return __builtin_amdgcn_exp2f(x);  // v_exp_f32
}

__device__ __forceinline__ f16x2 pk_f16(float a, float b) {
  return __builtin_bit_cast(f16x2, __builtin_amdgcn_cvt_pkrtz(a, b));  // v_cvt_pkrtz_f16_f32
}

// ---------------- fp32 -> f16 conversion ----------------
__global__ __launch_bounds__(256) void cvt_kernel(const float* __restrict__ src,
                                                  f16* __restrict__ dst, int n4) {
  int i = blockIdx.x * 256 + threadIdx.x;
  if (i >= n4) return;
  float4 v = ((const float4*)src)[i];
  f16x4 h = {(f16)v.x, (f16)v.y, (f16)v.z, (f16)v.w};
  ((f16x4*)dst)[i] = h;
}

// ---------------- fused QKV projection GEMM ----------------
// Outputs stored in MFMA fragment order (R5 layout — coalesced 16B/lane), f16:
//  QF/KF[bh][st=s/16][lane][dt*4+jj] = M[s=st*16+(lane&15)][dh=dt*16+(lane>>4)*4+jj]
//  VF[bh][kt=key/16][lane][dt*4+jj]  = V[key=kt*16+(lane>>4)*4+jj][dh=dt*16+(lane&15)]
//  Q is pre-scaled by 1/8*log2(e) (softmax fold).
__global__ __launch_bounds__(256) void qkv_gemm(
    const f16* __restrict__ Xh, const f16* __restrict__ Wh,
    const float* __restrict__ bq, const float* __restrict__ bk,
    const float* __restrict__ bv,
    f16* __restrict__ QF, f16* __restrict__ KF, f16* __restrict__ VF) {
  __shared__ f16 Ah[128 * 32];
  __shared__ f16 Bh[128 * 32];
  const int t = threadIdx.x;
  const int tileM = blockIdx.x * 128;
  const int nGlob = blockIdx.y * 128;
  const int mat = nGlob >> 10;
  const int col0 = nGlob & 1023;
  const int wave = t >> 6, lane = t & 63;
  const int mOff = (wave & 1) * 64, nOff = (wave >> 1) * 64;
  const int lr = lane & 15, quad = lane >> 4;

  f32x4 acc[4][4];
#pragma unroll
  for (int i = 0; i < 4; i++)
#pragma unroll
    for (int j = 0; j < 4; j++) acc[i][j] = f32x4{0.f, 0.f, 0.f, 0.f};

  const int srow = t >> 2, schunk = (t & 3) * 8;
  const f16* ag = Xh + (size_t)(tileM + srow) * ND + schunk;
  const f16* bg = Wh + (size_t)mat * ND * ND + (size_t)(col0 + srow) * ND + schunk;
  const bool qk = (mat < 2);

  for (int kk = 0; kk < ND; kk += 32) {
    __syncthreads();
    gl2lds16(ag + kk, Ah + t * 8);
    gl2lds16(ag + (size_t)64 * ND + kk, Ah + 2048 + t * 8);
    gl2lds16(bg + kk, Bh + t * 8);
    gl2lds16(bg + (size_t)64 * ND + kk, Bh + 2048 + t * 8);
    __syncthreads();
    f16x8 af[4], bf[4];
#pragma unroll
    for (int i = 0; i < 4; i++)
      af[i] = *(const f16x8*)(Ah + (mOff + i * 16 + lr) * 32 + quad * 8);
#pragma unroll
    for (int j = 0; j < 4; j++)
      bf[j] = *(const f16x8*)(Bh + (nOff + j * 16 + lr) * 32 + quad * 8);
    if (qk) {
#pragma unroll
      for (int i = 0; i < 4; i++)
#pragma unroll
        for (int j = 0; j < 4; j++)
          acc[i][j] = __builtin_amdgcn_mfma_f32_16x16x32_f16(bf[j], af[i], acc[i][j], 0, 0, 0);
    } else {
#pragma unroll
      for (int i = 0; i < 4; i++)
#pragma unroll
        for (int j = 0; j < 4; j++)
          acc[i][j] = __builtin_amdgcn_mfma_f32_16x16x32_f16(af[i], bf[j], acc[i][j], 0, 0, 0);
    }
  }

  if (qk) {
    // acc[i][j][r] = C[dh_n = col0+nOff+j*16+quad*4+r][s = tileM+mOff+i*16+lr]
    const float* bias = (mat == 0) ? bq : bk;
    f16* dst = (mat == 0) ? QF : KF;
    const float sc = (mat == 0) ? 0.18033688f : 1.0f;  // 1/8*log2(e) folded into Q
#pragma unroll
    for (int j = 0; j < 4; j++) {
      int n0 = col0 + nOff + j * 16;
      int h = n0 >> 6, dt = (n0 >> 4) & 3;
      float4 bb = *(const float4*)(bias + n0 + quad * 4);
#pragma unroll
      for (int i = 0; i < 4; i++) {
        int sF = tileM + mOff + i * 16;
        int b = sF >> 11, st = (sF & 2047) >> 4;
        int bh = b * NH + h;
        f16x4 v;
#pragma unroll
        for (int r = 0; r < 4; r++) v[r] = (f16)((acc[i][j][r] + (&bb.x)[r]) * sc);
        *(f16x4*)(dst + ((size_t)(bh * 128 + st) * 64 + lane) * 16 + dt * 4) = v;
      }
    }
  } else {
    // acc[i][j][r] = C[key = tileM+mOff+i*16+quad*4+r][dh_n = col0+nOff+j*16+lr]
#pragma unroll
    for (int j = 0; j < 4; j++) {
      int n = col0 + nOff + j * 16 + lr;
      int h = n >> 6, dt = (n >> 4) & 3;
      float bb = bv[n];
#pragma unroll
      for (int i = 0; i < 4; i++) {
        int sF = tileM + mOff + i * 16;
        int b = sF >> 11, kt = (sF & 2047) >> 4;
        int bh = b * NH + h;
        f16x4 v;
#pragma unroll
        for (int r = 0; r < 4; r++) v[r] = (f16)(acc[i][j][r] + bb);
        *(f16x4*)(VF + ((size_t)(bh * 128 + kt) * 64 + lane) * 16 + dt * 4) = v;
      }
    }
  }
}

// ---------------- flash attention: zero LDS, zero barriers ----------------
// R5 structure (coalesced frag-order loads, K=16 MFMAs) with VALU cuts:
// scale folded into Q, lsum via P.ones MFMA, pkrtz P pack, 2-bank prefetch.
__global__ __launch_bounds__(256) void attn_kernel(
    const f16* __restrict__ QF, const f16* __restrict__ KF,
    const f16* __restrict__ VF, float* __restrict__ out) {
  const int t = threadIdx.x, wave = t >> 6, lane = t & 63;
  const int lr = lane & 15, quad = lane >> 4;
  const int qb = blockIdx.x, bh = blockIdx.y;
  const int bb = bh >> 4, hh = bh & 15;
  const size_t bhOff = (size_t)bh * 131072;  // 128 tiles * 64 lanes * 16
  const f16* Qb = QF + bhOff;
  const f16* Kp = KF + bhOff + (size_t)lane * 16;
  const f16* Vp = VF + bhOff + (size_t)lane * 16;
  const int st0 = qb * 8 + wave * 2;

  // Q B-frags (n=q=lane&15, k=dh=quad*4+jj), register-resident, pre-scaled
  f16x4 qf[2][4];
#pragma unroll
  for (int qt = 0; qt < 2; qt++) {
    f16x8 lo = *(const f16x8*)(Qb + ((size_t)(st0 + qt) * 64 + lane) * 16);
    f16x8 hi = *(const f16x8*)(Qb + ((size_t)(st0 + qt) * 64 + lane) * 16 + 8);
    qf[qt][0] = __builtin_shufflevector(lo, lo, 0, 1, 2, 3);
    qf[qt][1] = __builtin_shufflevector(lo, lo, 4, 5, 6, 7);
    qf[qt][2] = __builtin_shufflevector(hi, hi, 0, 1, 2, 3);
    qf[qt][3] = __builtin_shufflevector(hi, hi, 4, 5, 6, 7);
  }

  f32x4 o[2][4];
#pragma unroll
  for (int qt = 0; qt < 2; qt++)
#pragma unroll
    for (int dt = 0; dt < 4; dt++) o[qt][dt] = f32x4{0.f, 0.f, 0.f, 0.f};
  f32x4 lacc[2] = {f32x4{0.f, 0.f, 0.f, 0.f}, f32x4{0.f, 0.f, 0.f, 0.f}};
  const f16x4 ones = {(f16)1.f, (f16)1.f, (f16)1.f, (f16)1.f};

  auto compute = [&](f16x8 k0, f16x8 k1, f16x8 v0, f16x8 v1) {
    f16x4 ka[4], vv[4];
    ka[0] = __builtin_shufflevector(k0, k0, 0, 1, 2, 3);
    ka[1] = __builtin_shufflevector(k0, k0, 4, 5, 6, 7);
    ka[2] = __builtin_shufflevector(k1, k1, 0, 1, 2, 3);
    ka[3] = __builtin_shufflevector(k1, k1, 4, 5, 6, 7);
    vv[0] = __builtin_shufflevector(v0, v0, 0, 1, 2, 3);
    vv[1] = __builtin_shufflevector(v0, v0, 4, 5, 6, 7);
    vv[2] = __builtin_shufflevector(v1, v1, 0, 1, 2, 3);
    vv[3] = __builtin_shufflevector(v1, v1, 4, 5, 6, 7);
    // S^T[key][q]: A=K-frag, B=Q-frag (scale pre-folded into Q)
    f32x4 s[2] = {f32x4{0.f, 0.f, 0.f, 0.f}, f32x4{0.f, 0.f, 0.f, 0.f}};
#pragma unroll
    for (int dt = 0; dt < 4; dt++) {
      s[0] = __builtin_amdgcn_mfma_f32_16x16x16f16(ka[dt], qf[0][dt], s[0], 0, 0, 0);
      s[1] = __builtin_amdgcn_mfma_f32_16x16x16f16(ka[dt], qf[1][dt], s[1], 0, 0, 0);
    }
    // p = exp2(s); pack with v_cvt_pkrtz; lsum accumulated by MFMA below
    f16x4 p[2];
#pragma unroll
    for (int qt = 0; qt < 2; qt++) {
      f16x2 plo = pk_f16(fast_exp2(s[qt][0]), fast_exp2(s[qt][1]));
      f16x2 phi = pk_f16(fast_exp2(s[qt][2]), fast_exp2(s[qt][3]));
      p[qt] = __builtin_shufflevector(plo, phi, 0, 1, 2, 3);
    }
    // O += P.V and lsum += P.1 (both as MFMA; P is already the A-frag)
#pragma unroll
    for (int dt = 0; dt < 4; dt++) {
      o[0][dt] = __builtin_amdgcn_mfma_f32_16x16x16f16(p[0], vv[dt], o[0][dt], 0, 0, 0);
      o[1][dt] = __builtin_amdgcn_mfma_f32_16x16x16f16(p[1], vv[dt], o[1][dt], 0, 0, 0);
    }
    lacc[0] = __builtin_amdgcn_mfma_f32_16x16x16f16(p[0], ones, lacc[0], 0, 0, 0);
    lacc[1] = __builtin_amdgcn_mfma_f32_16x16x16f16(p[1], ones, lacc[1], 0, 0, 0);
  };

  // two-bank software pipeline (no register rotation)
  f16x8 kA0 = *(const f16x8*)(Kp);
  f16x8 kA1 = *(const f16x8*)(Kp + 8);
  f16x8 vA0 = *(const f16x8*)(Vp);
  f16x8 vA1 = *(const f16x8*)(Vp + 8);

  for (int kt = 0; kt < 128; kt += 2) {
    f16x8 kB0 = *(const f16x8*)(Kp + (size_t)(kt + 1) * 1024);
    f16x8 kB1 = *(const f16x8*)(Kp + (size_t)(kt + 1) * 1024 + 8);
    f16x8 vB0 = *(const f16x8*)(Vp + (size_t)(kt + 1) * 1024);
    f16x8 vB1 = *(const f16x8*)(Vp + (size_t)(kt + 1) * 1024 + 8);
    compute(kA0, kA1, vA0, vA1);
    const int kn = (kt + 2) & 127;  // branchless wrap keeps address in-bounds
    kA0 = *(const f16x8*)(Kp + (size_t)kn * 1024);
    kA1 = *(const f16x8*)(Kp + (size_t)kn * 1024 + 8);
    vA0 = *(const f16x8*)(Vp + (size_t)kn * 1024);
    vA1 = *(const f16x8*)(Vp + (size_t)kn * 1024 + 8);
    compute(kB0, kB1, vB0, vB1);
  }

  // lacc C-layout: lane holds q=quad*4+r (all cols equal) -> no shuffles at all
#pragma unroll
  for (int qt = 0; qt < 2; qt++) {
#pragma unroll
    for (int r = 0; r < 4; r++) {
      float inv = 1.0f / lacc[qt][r];
      int q = qb * 128 + wave * 32 + qt * 16 + quad * 4 + r;
#pragma unroll
      for (int dt = 0; dt < 4; dt++)
        out[((size_t)bb * NS + q) * ND + hh * 64 + dt * 16 + lr] = o[qt][dt][r] * inv;
    }
  }
}

extern "C" void kernel_launch(void* const* d_in, const int* in_sizes, int n_in,
                              void* d_out, int out_size, void* d_ws, size_t ws_size,
                              hipStream_t stream) {
  const float* X  = (const float*)d_in[0];
  const float* Wq = (const float*)d_in[1];
  const float* bq = (const float*)d_in[2];
  const float* Wk = (const float*)d_in[3];
  const float* bk = (const float*)d_in[4];
  const float* Wv = (const float*)d_in[5];
  const float* bv = (const float*)d_in[6];
  float* out = (float*)d_out;

  // ws: Xh 16MB | Wh 6MB | QF 16MB | KF 16MB | VF 16MB = 70MB
  f16* Xh = (f16*)d_ws;
  f16* Wh = (f16*)((char*)d_ws + (size_t)(16u << 20));
  f16* QF = (f16*)((char*)d_ws + (size_t)(22u << 20));
  f16* KF = (f16*)((char*)d_ws + (size_t)(38u << 20));
  f16* VF = (f16*)((char*)d_ws + (size_t)(54u << 20));

  cvt_kernel<<<8192, 256, 0, stream>>>(X, Xh, 2097152);
  cvt_kernel<<<1024, 256, 0, stream>>>(Wq, Wh, 262144);
  cvt_kernel<<<1024, 256, 0, stream>>>(Wk, Wh + (1u << 20), 262144);
  cvt_kernel<<<1024, 256, 0, stream>>>(Wv, Wh + (2u << 20), 262144);
  qkv_gemm<<<dim3(64, 24), 256, 0, stream>>>(Xh, Wh, bq, bk, bv, QF, KF, VF);
  attn_kernel<<<dim3(16, 64), 256, 0, stream>>>(QF, KF, VF, out);
}

// Round 9
// 269.569 us; speedup vs baseline: 1.2141x; 1.0656x over previous
//
#include <hip/hip_runtime.h>

typedef _Float16 f16;
typedef f16 f16x2 __attribute__((ext_vector_type(2)));
typedef f16 f16x4 __attribute__((ext_vector_type(4)));
typedef f16 f16x8 __attribute__((ext_vector_type(8)));
typedef float f32x4 __attribute__((ext_vector_type(4)));

#define NB 4
#define NS 2048
#define ND 1024
#define NH 16
#define NDH 64

__device__ __forceinline__ void gl2lds16(const void* g, void* l) {
  __builtin_amdgcn_global_load_lds(
      (const __attribute__((address_space(1))) unsigned int*)g,
      (__attribute__((address_space(3))) unsigned int*)l, 16, 0, 0);
}

__device__ __forceinline__ float fast_exp2(float x) {
  return __builtin_amdgcn_exp2f(x);  // v_exp_f32
}

__device__ __forceinline__ f16x2 pk_f16(float a, float b) {
  return __builtin_bit_cast(f16x2, __builtin_amdgcn_cvt_pkrtz(a, b));  // v_cvt_pkrtz_f16_f32
}

// ---------------- fp32 -> f16 conversion (all 4 inputs, one launch) ----------
__global__ __launch_bounds__(256) void cvt_all(
    const float* __restrict__ X, const float* __restrict__ Wq,
    const float* __restrict__ Wk, const float* __restrict__ Wv,
    f16* __restrict__ Xh, f16* __restrict__ Wh) {
  int b = blockIdx.x;
  const float* src;
  f16* dst;
  int off;
  if (b < 8192)       { src = X;  dst = Xh;               off = 0; }
  else if (b < 9216)  { src = Wq; dst = Wh;               off = 8192; }
  else if (b < 10240) { src = Wk; dst = Wh + (1u << 20);  off = 9216; }
  else                { src = Wv; dst = Wh + (2u << 20);  off = 10240; }
  int i = (b - off) * 256 + threadIdx.x;
  float4 v = ((const float4*)src)[i];
  f16x4 h = {(f16)v.x, (f16)v.y, (f16)v.z, (f16)v.w};
  ((f16x4*)dst)[i] = h;
}

// ---------------- fused QKV projection GEMM ----------------
// QF/KF stored in K=32 MFMA fragment order (coalesced 16B/lane in attn):
//   frag f covers dh f*32..f*32+31 of a 16-row tile; lane L holds
//   M[row = tile*16 + (L&15)][dh = f*32 + (L>>4)*8 + j], j=0..7 (16B).
//   Address: (((bh*128+tile)*2+f)*64+L)*8 + j.   Q pre-scaled by 1/8*log2(e).
// VF stored in K=16 PV B-frag order (unchanged):
//   VF[bh][kt][lane][dt*4+jj] = V[key=kt*16+(lane>>4)*4+jj][dh=dt*16+(lane&15)]
__global__ __launch_bounds__(256) void qkv_gemm(
    const f16* __restrict__ Xh, const f16* __restrict__ Wh,
    const float* __restrict__ bq, const float* __restrict__ bk,
    const float* __restrict__ bv,
    f16* __restrict__ QF, f16* __restrict__ KF, f16* __restrict__ VF) {
  __shared__ f16 Ah[128 * 32];
  __shared__ f16 Bh[128 * 32];
  const int t = threadIdx.x;
  const int tileM = blockIdx.x * 128;
  const int nGlob = blockIdx.y * 128;
  const int mat = nGlob >> 10;
  const int col0 = nGlob & 1023;
  const int wave = t >> 6, lane = t & 63;
  const int mOff = (wave & 1) * 64, nOff = (wave >> 1) * 64;
  const int lr = lane & 15, quad = lane >> 4;

  f32x4 acc[4][4];
#pragma unroll
  for (int i = 0; i < 4; i++)
#pragma unroll
    for (int j = 0; j < 4; j++) acc[i][j] = f32x4{0.f, 0.f, 0.f, 0.f};

  const int srow = t >> 2, schunk = (t & 3) * 8;
  const f16* ag = Xh + (size_t)(tileM + srow) * ND + schunk;
  const f16* bg = Wh + (size_t)mat * ND * ND + (size_t)(col0 + srow) * ND + schunk;
  const bool qk = (mat < 2);

  for (int kk = 0; kk < ND; kk += 32) {
    __syncthreads();
    gl2lds16(ag + kk, Ah + t * 8);
    gl2lds16(ag + (size_t)64 * ND + kk, Ah + 2048 + t * 8);
    gl2lds16(bg + kk, Bh + t * 8);
    gl2lds16(bg + (size_t)64 * ND + kk, Bh + 2048 + t * 8);
    __syncthreads();
    f16x8 af[4], bf[4];
#pragma unroll
    for (int i = 0; i < 4; i++)
      af[i] = *(const f16x8*)(Ah + (mOff + i * 16 + lr) * 32 + quad * 8);
#pragma unroll
    for (int j = 0; j < 4; j++)
      bf[j] = *(const f16x8*)(Bh + (nOff + j * 16 + lr) * 32 + quad * 8);
    if (qk) {
#pragma unroll
      for (int i = 0; i < 4; i++)
#pragma unroll
        for (int j = 0; j < 4; j++)
          acc[i][j] = __builtin_amdgcn_mfma_f32_16x16x32_f16(bf[j], af[i], acc[i][j], 0, 0, 0);
    } else {
#pragma unroll
      for (int i = 0; i < 4; i++)
#pragma unroll
        for (int j = 0; j < 4; j++)
          acc[i][j] = __builtin_amdgcn_mfma_f32_16x16x32_f16(af[i], bf[j], acc[i][j], 0, 0, 0);
    }
  }

  if (qk) {
    // acc[i][j][r] = C[dh_n = col0+nOff+j*16+quad*4+r][row = tileM+mOff+i*16+lr]
    // dt16 == j (col0 mult of 128, nOff in {0,64}).
    // Target: frag f=j>>1, lane lam=lr+16*((2j+(quad>>1))&3), byte jstart=(quad&1)*4.
    const float* bias = (mat == 0) ? bq : bk;
    f16* dst = (mat == 0) ? QF : KF;
    const float sc = (mat == 0) ? 0.18033688f : 1.0f;  // 1/8*log2(e) folded into Q
    const int jstart = (quad & 1) * 4;
#pragma unroll
    for (int j = 0; j < 4; j++) {
      int n0 = col0 + nOff + j * 16;
      int h = n0 >> 6;
      int f = j >> 1;
      int lam = lr + 16 * ((2 * j + (quad >> 1)) & 3);
      float4 bb = *(const float4*)(bias + n0 + quad * 4);
#pragma unroll
      for (int i = 0; i < 4; i++) {
        int sF = tileM + mOff + i * 16;
        int b = sF >> 11, st = (sF & 2047) >> 4;
        int bh = b * NH + h;
        f16x4 v;
#pragma unroll
        for (int r = 0; r < 4; r++) v[r] = (f16)((acc[i][j][r] + (&bb.x)[r]) * sc);
        *(f16x4*)(dst + (((size_t)(bh * 128 + st) * 2 + f) * 64 + lam) * 8 + jstart) = v;
      }
    }
  } else {
    // acc[i][j][r] = C[key = tileM+mOff+i*16+quad*4+r][dh_n = col0+nOff+j*16+lr]
#pragma unroll
    for (int j = 0; j < 4; j++) {
      int n = col0 + nOff + j * 16 + lr;
      int h = n >> 6, dt = (n >> 4) & 3;
      float bb = bv[n];
#pragma unroll
      for (int i = 0; i < 4; i++) {
        int sF = tileM + mOff + i * 16;
        int b = sF >> 11, kt = (sF & 2047) >> 4;
        int bh = b * NH + h;
        f16x4 v;
#pragma unroll
        for (int r = 0; r < 4; r++) v[r] = (f16)(acc[i][j][r] + bb);
        *(f16x4*)(VF + ((size_t)(bh * 128 + kt) * 64 + lane) * 16 + dt * 4) = v;
      }
    }
  }
}

// ---------------- flash attention: zero LDS, zero barriers ----------------
// QK via K=32 MFMA (frag-order coalesced loads), PV via K=16 (P layout identity),
// lsum via P.ones MFMA, distance-2 prefetch in 2 banks (loads placed after
// the bank's last use -> ~1.5 iterations of slack).
__global__ __launch_bounds__(256) void attn_kernel(
    const f16* __restrict__ QF, const f16* __restrict__ KF,
    const f16* __restrict__ VF, float* __restrict__ out) {
  const int t = threadIdx.x, wave = t >> 6, lane = t & 63;
  const int lr = lane & 15, quad = lane >> 4;
  const int qb = blockIdx.x, bh = blockIdx.y;
  const int bb = bh >> 4, hh = bh & 15;
  const size_t bhOff = (size_t)bh * 131072;  // 128 tiles * 2 frags * 512
  const f16* Qp = QF + bhOff + (size_t)lane * 8;
  const f16* Kp = KF + bhOff + (size_t)lane * 8;
  const f16* Vp = VF + bhOff + (size_t)lane * 16;
  const int st0 = qb * 8 + wave * 2;

  // Q B-frags for K=32 (n=q=lane&15, k=dh=(lane>>4)*8+j + f*32), pre-scaled
  f16x8 qf[2][2];
#pragma unroll
  for (int qt = 0; qt < 2; qt++) {
    qf[qt][0] = *(const f16x8*)(Qp + (size_t)(st0 + qt) * 1024);
    qf[qt][1] = *(const f16x8*)(Qp + (size_t)(st0 + qt) * 1024 + 512);
  }

  f32x4 o[2][4];
#pragma unroll
  for (int qt = 0; qt < 2; qt++)
#pragma unroll
    for (int dt = 0; dt < 4; dt++) o[qt][dt] = f32x4{0.f, 0.f, 0.f, 0.f};
  f32x4 lacc[2] = {f32x4{0.f, 0.f, 0.f, 0.f}, f32x4{0.f, 0.f, 0.f, 0.f}};
  const f16x4 ones = {(f16)1.f, (f16)1.f, (f16)1.f, (f16)1.f};

  // bank registers
  f16x8 kA0, kA1, vA0, vA1, kB0, kB1, vB0, vB1;
  kA0 = *(const f16x8*)(Kp);
  kA1 = *(const f16x8*)(Kp + 512);
  vA0 = *(const f16x8*)(Vp);
  vA1 = *(const f16x8*)(Vp + 8);
  kB0 = *(const f16x8*)(Kp + 1024);
  kB1 = *(const f16x8*)(Kp + 1024 + 512);
  vB0 = *(const f16x8*)(Vp + 1024);
  vB1 = *(const f16x8*)(Vp + 1024 + 8);

  for (int kt = 0; kt < 128; kt += 2) {
    // ---- iter kt : bank A ----
    {
      f32x4 s0 = {0.f, 0.f, 0.f, 0.f}, s1 = {0.f, 0.f, 0.f, 0.f};
      s0 = __builtin_amdgcn_mfma_f32_16x16x32_f16(kA0, qf[0][0], s0, 0, 0, 0);
      s0 = __builtin_amdgcn_mfma_f32_16x16x32_f16(kA1, qf[0][1], s0, 0, 0, 0);
      s1 = __builtin_amdgcn_mfma_f32_16x16x32_f16(kA0, qf[1][0], s1, 0, 0, 0);
      s1 = __builtin_amdgcn_mfma_f32_16x16x32_f16(kA1, qf[1][1], s1, 0, 0, 0);
      // kA free -> prefetch tile kt+2 (distance 2)
      const size_t nk = (size_t)((kt + 2) & 127) * 1024;
      kA0 = *(const f16x8*)(Kp + nk);
      kA1 = *(const f16x8*)(Kp + nk + 512);
      f16x2 p0lo = pk_f16(fast_exp2(s0[0]), fast_exp2(s0[1]));
      f16x2 p0hi = pk_f16(fast_exp2(s0[2]), fast_exp2(s0[3]));
      f16x2 p1lo = pk_f16(fast_exp2(s1[0]), fast_exp2(s1[1]));
      f16x2 p1hi = pk_f16(fast_exp2(s1[2]), fast_exp2(s1[3]));
      f16x4 p0 = __builtin_shufflevector(p0lo, p0hi, 0, 1, 2, 3);
      f16x4 p1 = __builtin_shufflevector(p1lo, p1hi, 0, 1, 2, 3);
      f16x4 vv[4];
      vv[0] = __builtin_shufflevector(vA0, vA0, 0, 1, 2, 3);
      vv[1] = __builtin_shufflevector(vA0, vA0, 4, 5, 6, 7);
      vv[2] = __builtin_shufflevector(vA1, vA1, 0, 1, 2, 3);
      vv[3] = __builtin_shufflevector(vA1, vA1, 4, 5, 6, 7);
#pragma unroll
      for (int dt = 0; dt < 4; dt++) {
        o[0][dt] = __builtin_amdgcn_mfma_f32_16x16x16f16(p0, vv[dt], o[0][dt], 0, 0, 0);
        o[1][dt] = __builtin_amdgcn_mfma_f32_16x16x16f16(p1, vv[dt], o[1][dt], 0, 0, 0);
      }
      lacc[0] = __builtin_amdgcn_mfma_f32_16x16x16f16(p0, ones, lacc[0], 0, 0, 0);
      lacc[1] = __builtin_amdgcn_mfma_f32_16x16x16f16(p1, ones, lacc[1], 0, 0, 0);
      // vA free -> prefetch tile kt+2
      vA0 = *(const f16x8*)(Vp + nk);
      vA1 = *(const f16x8*)(Vp + nk + 8);
    }
    // ---- iter kt+1 : bank B ----
    {
      f32x4 s0 = {0.f, 0.f, 0.f, 0.f}, s1 = {0.f, 0.f, 0.f, 0.f};
      s0 = __builtin_amdgcn_mfma_f32_16x16x32_f16(kB0, qf[0][0], s0, 0, 0, 0);
      s0 = __builtin_amdgcn_mfma_f32_16x16x32_f16(kB1, qf[0][1], s0, 0, 0, 0);
      s1 = __builtin_amdgcn_mfma_f32_16x16x32_f16(kB0, qf[1][0], s1, 0, 0, 0);
      s1 = __builtin_amdgcn_mfma_f32_16x16x32_f16(kB1, qf[1][1], s1, 0, 0, 0);
      const size_t nk = (size_t)((kt + 3) & 127) * 1024;
      kB0 = *(const f16x8*)(Kp + nk);
      kB1 = *(const f16x8*)(Kp + nk + 512);
      f16x2 p0lo = pk_f16(fast_exp2(s0[0]), fast_exp2(s0[1]));
      f16x2 p0hi = pk_f16(fast_exp2(s0[2]), fast_exp2(s0[3]));
      f16x2 p1lo = pk_f16(fast_exp2(s1[0]), fast_exp2(s1[1]));
      f16x2 p1hi = pk_f16(fast_exp2(s1[2]), fast_exp2(s1[3]));
      f16x4 p0 = __builtin_shufflevector(p0lo, p0hi, 0, 1, 2, 3);
      f16x4 p1 = __builtin_shufflevector(p1lo, p1hi, 0, 1, 2, 3);
      f16x4 vv[4];
      vv[0] = __builtin_shufflevector(vB0, vB0, 0, 1, 2, 3);
      vv[1] = __builtin_shufflevector(vB0, vB0, 4, 5, 6, 7);
      vv[2] = __builtin_shufflevector(vB1, vB1, 0, 1, 2, 3);
      vv[3] = __builtin_shufflevector(vB1, vB1, 4, 5, 6, 7);
#pragma unroll
      for (int dt = 0; dt < 4; dt++) {
        o[0][dt] = __builtin_amdgcn_mfma_f32_16x16x16f16(p0, vv[dt], o[0][dt], 0, 0, 0);
        o[1][dt] = __builtin_amdgcn_mfma_f32_16x16x16f16(p1, vv[dt], o[1][dt], 0, 0, 0);
      }
      lacc[0] = __builtin_amdgcn_mfma_f32_16x16x16f16(p0, ones, lacc[0], 0, 0, 0);
      lacc[1] = __builtin_amdgcn_mfma_f32_16x16x16f16(p1, ones, lacc[1], 0, 0, 0);
      vB0 = *(const f16x8*)(Vp + nk);
      vB1 = *(const f16x8*)(Vp + nk + 8);
    }
  }

  // lacc C-layout: lane holds q=quad*4+r (all cols equal) -> no shuffles
#pragma unroll
  for (int qt = 0; qt < 2; qt++) {
#pragma unroll
    for (int r = 0; r < 4; r++) {
      float inv = 1.0f / lacc[qt][r];
      int q = qb * 128 + wave * 32 + qt * 16 + quad * 4 + r;
#pragma unroll
      for (int dt = 0; dt < 4; dt++)
        out[((size_t)bb * NS + q) * ND + hh * 64 + dt * 16 + lr] = o[qt][dt][r] * inv;
    }
  }
}

extern "C" void kernel_launch(void* const* d_in, const int* in_sizes, int n_in,
                              void* d_out, int out_size, void* d_ws, size_t ws_size,
                              hipStream_t stream) {
  const float* X  = (const float*)d_in[0];
  const float* Wq = (const float*)d_in[1];
  const float* bq = (const float*)d_in[2];
  const float* Wk = (const float*)d_in[3];
  const float* bk = (const float*)d_in[4];
  const float* Wv = (const float*)d_in[5];
  const float* bv = (const float*)d_in[6];
  float* out = (float*)d_out;

  // ws: Xh 16MB | Wh 6MB | QF 16MB | KF 16MB | VF 16MB = 70MB
  f16* Xh = (f16*)d_ws;
  f16* Wh = (f16*)((char*)d_ws + (size_t)(16u << 20));
  f16* QF = (f16*)((char*)d_ws + (size_t)(22u << 20));
  f16* KF = (f16*)((char*)d_ws + (size_t)(38u << 20));
  f16* VF = (f16*)((char*)d_ws + (size_t)(54u << 20));

  cvt_all<<<11264, 256, 0, stream>>>(X, Wq, Wk, Wv, Xh, Wh);
  qkv_gemm<<<dim3(64, 24), 256, 0, stream>>>(Xh, Wh, bq, bk, bv, QF, KF, VF);
  attn_kernel<<<dim3(16, 64), 256, 0, stream>>>(QF, KF, VF, out);
}

// Round 10
// 263.366 us; speedup vs baseline: 1.2427x; 1.0236x over previous
//
#include <hip/hip_runtime.h>

typedef _Float16 f16;
typedef f16 f16x2 __attribute__((ext_vector_type(2)));
typedef f16 f16x4 __attribute__((ext_vector_type(4)));
typedef f16 f16x8 __attribute__((ext_vector_type(8)));
typedef float f32x4 __attribute__((ext_vector_type(4)));

#define NB 4
#define NS 2048
#define ND 1024
#define NH 16
#define NDH 64

__device__ __forceinline__ void gl2lds16(const void* g, void* l) {
  __builtin_amdgcn_global_load_lds(
      (const __attribute__((address_space(1))) unsigned int*)g,
      (__attribute__((address_space(3))) unsigned int*)l, 16, 0, 0);
}

__device__ __forceinline__ float fast_exp2(float x) {
  return __builtin_amdgcn_exp2f(x);  // v_exp_f32
}

__device__ __forceinline__ f16x2 pk_f16(float a, float b) {
  return __builtin_bit_cast(f16x2, __builtin_amdgcn_cvt_pkrtz(a, b));  // v_cvt_pkrtz_f16_f32
}

// ---------------- fp32 -> f16 conversion (all 4 inputs, one launch) ----------
__global__ __launch_bounds__(256) void cvt_all(
    const float* __restrict__ X, const float* __restrict__ Wq,
    const float* __restrict__ Wk, const float* __restrict__ Wv,
    f16* __restrict__ Xh, f16* __restrict__ Wh) {
  int b = blockIdx.x;
  const float* src;
  f16* dst;
  int off;
  if (b < 8192)       { src = X;  dst = Xh;               off = 0; }
  else if (b < 9216)  { src = Wq; dst = Wh;               off = 8192; }
  else if (b < 10240) { src = Wk; dst = Wh + (1u << 20);  off = 9216; }
  else                { src = Wv; dst = Wh + (2u << 20);  off = 10240; }
  int i = (b - off) * 256 + threadIdx.x;
  float4 v = ((const float4*)src)[i];
  f16x4 h = {(f16)v.x, (f16)v.y, (f16)v.z, (f16)v.w};
  ((f16x4*)dst)[i] = h;
}

// ---------------- fused QKV projection GEMM ----------------
// QF/KF stored in K=32 MFMA fragment order (coalesced 16B/lane in attn):
//   frag f covers dh f*32..f*32+31 of a 16-row tile; lane L holds
//   M[row = tile*16 + (L&15)][dh = f*32 + (L>>4)*8 + j], j=0..7 (16B).
//   Address: (((bh*128+tile)*2+f)*64+L)*8 + j.   Q pre-scaled by 1/8*log2(e).
// VF stored in K=16 PV B-frag order (unchanged):
//   VF[bh][kt][lane][dt*4+jj] = V[key=kt*16+(lane>>4)*4+jj][dh=dt*16+(lane&15)]
__global__ __launch_bounds__(256) void qkv_gemm(
    const f16* __restrict__ Xh, const f16* __restrict__ Wh,
    const float* __restrict__ bq, const float* __restrict__ bk,
    const float* __restrict__ bv,
    f16* __restrict__ QF, f16* __restrict__ KF, f16* __restrict__ VF) {
  __shared__ f16 Ah[128 * 32];
  __shared__ f16 Bh[128 * 32];
  const int t = threadIdx.x;
  const int tileM = blockIdx.x * 128;
  const int nGlob = blockIdx.y * 128;
  const int mat = nGlob >> 10;
  const int col0 = nGlob & 1023;
  const int wave = t >> 6, lane = t & 63;
  const int mOff = (wave & 1) * 64, nOff = (wave >> 1) * 64;
  const int lr = lane & 15, quad = lane >> 4;

  f32x4 acc[4][4];
#pragma unroll
  for (int i = 0; i < 4; i++)
#pragma unroll
    for (int j = 0; j < 4; j++) acc[i][j] = f32x4{0.f, 0.f, 0.f, 0.f};

  const int srow = t >> 2, schunk = (t & 3) * 8;
  const f16* ag = Xh + (size_t)(tileM + srow) * ND + schunk;
  const f16* bg = Wh + (size_t)mat * ND * ND + (size_t)(col0 + srow) * ND + schunk;
  const bool qk = (mat < 2);

  for (int kk = 0; kk < ND; kk += 32) {
    __syncthreads();
    gl2lds16(ag + kk, Ah + t * 8);
    gl2lds16(ag + (size_t)64 * ND + kk, Ah + 2048 + t * 8);
    gl2lds16(bg + kk, Bh + t * 8);
    gl2lds16(bg + (size_t)64 * ND + kk, Bh + 2048 + t * 8);
    __syncthreads();
    f16x8 af[4], bf[4];
#pragma unroll
    for (int i = 0; i < 4; i++)
      af[i] = *(const f16x8*)(Ah + (mOff + i * 16 + lr) * 32 + quad * 8);
#pragma unroll
    for (int j = 0; j < 4; j++)
      bf[j] = *(const f16x8*)(Bh + (nOff + j * 16 + lr) * 32 + quad * 8);
    if (qk) {
#pragma unroll
      for (int i = 0; i < 4; i++)
#pragma unroll
        for (int j = 0; j < 4; j++)
          acc[i][j] = __builtin_amdgcn_mfma_f32_16x16x32_f16(bf[j], af[i], acc[i][j], 0, 0, 0);
    } else {
#pragma unroll
      for (int i = 0; i < 4; i++)
#pragma unroll
        for (int j = 0; j < 4; j++)
          acc[i][j] = __builtin_amdgcn_mfma_f32_16x16x32_f16(af[i], bf[j], acc[i][j], 0, 0, 0);
    }
  }

  if (qk) {
    // acc[i][j][r] = C[dh_n = col0+nOff+j*16+quad*4+r][row = tileM+mOff+i*16+lr]
    // Target: frag f=j>>1, lane lam=lr+16*((2j+(quad>>1))&3), byte jstart=(quad&1)*4.
    const float* bias = (mat == 0) ? bq : bk;
    f16* dst = (mat == 0) ? QF : KF;
    const float sc = (mat == 0) ? 0.18033688f : 1.0f;  // 1/8*log2(e) folded into Q
    const int jstart = (quad & 1) * 4;
#pragma unroll
    for (int j = 0; j < 4; j++) {
      int n0 = col0 + nOff + j * 16;
      int h = n0 >> 6;
      int f = j >> 1;
      int lam = lr + 16 * ((2 * j + (quad >> 1)) & 3);
      float4 bb = *(const float4*)(bias + n0 + quad * 4);
#pragma unroll
      for (int i = 0; i < 4; i++) {
        int sF = tileM + mOff + i * 16;
        int b = sF >> 11, st = (sF & 2047) >> 4;
        int bh = b * NH + h;
        f16x4 v;
#pragma unroll
        for (int r = 0; r < 4; r++) v[r] = (f16)((acc[i][j][r] + (&bb.x)[r]) * sc);
        *(f16x4*)(dst + (((size_t)(bh * 128 + st) * 2 + f) * 64 + lam) * 8 + jstart) = v;
      }
    }
  } else {
    // acc[i][j][r] = C[key = tileM+mOff+i*16+quad*4+r][dh_n = col0+nOff+j*16+lr]
#pragma unroll
    for (int j = 0; j < 4; j++) {
      int n = col0 + nOff + j * 16 + lr;
      int h = n >> 6, dt = (n >> 4) & 3;
      float bb = bv[n];
#pragma unroll
      for (int i = 0; i < 4; i++) {
        int sF = tileM + mOff + i * 16;
        int b = sF >> 11, kt = (sF & 2047) >> 4;
        int bh = b * NH + h;
        f16x4 v;
#pragma unroll
        for (int r = 0; r < 4; r++) v[r] = (f16)(acc[i][j][r] + bb);
        *(f16x4*)(VF + ((size_t)(bh * 128 + kt) * 64 + lane) * 16 + dt * 4) = v;
      }
    }
  }
}

// ---------------- flash attention: zero LDS, zero barriers ----------------
// Wave owns 64 q (4 qtiles): K/V bytes feed 2x the outputs (L1 traffic halves),
// per-iter overhead amortized, 4 independent QK chains. grid (8,64).
__global__ __launch_bounds__(256) void attn_kernel(
    const f16* __restrict__ QF, const f16* __restrict__ KF,
    const f16* __restrict__ VF, float* __restrict__ out) {
  const int t = threadIdx.x, wave = t >> 6, lane = t & 63;
  const int lr = lane & 15, quad = lane >> 4;
  const int qb = blockIdx.x, bh = blockIdx.y;
  const int bb = bh >> 4, hh = bh & 15;
  const size_t bhOff = (size_t)bh * 131072;  // 128 tiles * 2 frags * 512
  const f16* Qp = QF + bhOff + (size_t)lane * 8;
  const f16* Kp = KF + bhOff + (size_t)lane * 8;
  const f16* Vp = VF + bhOff + (size_t)lane * 16;
  const int st0 = qb * 16 + wave * 4;

  // Q B-frags for K=32 (n=q=lane&15, k=dh=(lane>>4)*8+j + f*32), pre-scaled
  f16x8 qf[4][2];
#pragma unroll
  for (int qt = 0; qt < 4; qt++) {
    qf[qt][0] = *(const f16x8*)(Qp + (size_t)(st0 + qt) * 1024);
    qf[qt][1] = *(const f16x8*)(Qp + (size_t)(st0 + qt) * 1024 + 512);
  }

  f32x4 o[4][4];
#pragma unroll
  for (int qt = 0; qt < 4; qt++)
#pragma unroll
    for (int dt = 0; dt < 4; dt++) o[qt][dt] = f32x4{0.f, 0.f, 0.f, 0.f};
  f32x4 lacc[4];
#pragma unroll
  for (int qt = 0; qt < 4; qt++) lacc[qt] = f32x4{0.f, 0.f, 0.f, 0.f};
  const f16x4 ones = {(f16)1.f, (f16)1.f, (f16)1.f, (f16)1.f};

  // bank registers
  f16x8 kA0, kA1, vA0, vA1, kB0, kB1, vB0, vB1;
  kA0 = *(const f16x8*)(Kp);
  kA1 = *(const f16x8*)(Kp + 512);
  vA0 = *(const f16x8*)(Vp);
  vA1 = *(const f16x8*)(Vp + 8);
  kB0 = *(const f16x8*)(Kp + 1024);
  kB1 = *(const f16x8*)(Kp + 1024 + 512);
  vB0 = *(const f16x8*)(Vp + 1024);
  vB1 = *(const f16x8*)(Vp + 1024 + 8);

  for (int kt = 0; kt < 128; kt += 2) {
    // ---- iter kt : bank A ----
    {
      f32x4 s[4];
#pragma unroll
      for (int qt = 0; qt < 4; qt++) {
        s[qt] = f32x4{0.f, 0.f, 0.f, 0.f};
        s[qt] = __builtin_amdgcn_mfma_f32_16x16x32_f16(kA0, qf[qt][0], s[qt], 0, 0, 0);
        s[qt] = __builtin_amdgcn_mfma_f32_16x16x32_f16(kA1, qf[qt][1], s[qt], 0, 0, 0);
      }
      // kA free -> prefetch tile kt+2 (distance 2)
      const size_t nk = (size_t)((kt + 2) & 127) * 1024;
      kA0 = *(const f16x8*)(Kp + nk);
      kA1 = *(const f16x8*)(Kp + nk + 512);
      f16x4 p[4];
#pragma unroll
      for (int qt = 0; qt < 4; qt++) {
        f16x2 plo = pk_f16(fast_exp2(s[qt][0]), fast_exp2(s[qt][1]));
        f16x2 phi = pk_f16(fast_exp2(s[qt][2]), fast_exp2(s[qt][3]));
        p[qt] = __builtin_shufflevector(plo, phi, 0, 1, 2, 3);
      }
      f16x4 vv[4];
      vv[0] = __builtin_shufflevector(vA0, vA0, 0, 1, 2, 3);
      vv[1] = __builtin_shufflevector(vA0, vA0, 4, 5, 6, 7);
      vv[2] = __builtin_shufflevector(vA1, vA1, 0, 1, 2, 3);
      vv[3] = __builtin_shufflevector(vA1, vA1, 4, 5, 6, 7);
#pragma unroll
      for (int dt = 0; dt < 4; dt++)
#pragma unroll
        for (int qt = 0; qt < 4; qt++)
          o[qt][dt] = __builtin_amdgcn_mfma_f32_16x16x16f16(p[qt], vv[dt], o[qt][dt], 0, 0, 0);
#pragma unroll
      for (int qt = 0; qt < 4; qt++)
        lacc[qt] = __builtin_amdgcn_mfma_f32_16x16x16f16(p[qt], ones, lacc[qt], 0, 0, 0);
      // vA free -> prefetch tile kt+2
      vA0 = *(const f16x8*)(Vp + nk);
      vA1 = *(const f16x8*)(Vp + nk + 8);
    }
    // ---- iter kt+1 : bank B ----
    {
      f32x4 s[4];
#pragma unroll
      for (int qt = 0; qt < 4; qt++) {
        s[qt] = f32x4{0.f, 0.f, 0.f, 0.f};
        s[qt] = __builtin_amdgcn_mfma_f32_16x16x32_f16(kB0, qf[qt][0], s[qt], 0, 0, 0);
        s[qt] = __builtin_amdgcn_mfma_f32_16x16x32_f16(kB1, qf[qt][1], s[qt], 0, 0, 0);
      }
      const size_t nk = (size_t)((kt + 3) & 127) * 1024;
      kB0 = *(const f16x8*)(Kp + nk);
      kB1 = *(const f16x8*)(Kp + nk + 512);
      f16x4 p[4];
#pragma unroll
      for (int qt = 0; qt < 4; qt++) {
        f16x2 plo = pk_f16(fast_exp2(s[qt][0]), fast_exp2(s[qt][1]));
        f16x2 phi = pk_f16(fast_exp2(s[qt][2]), fast_exp2(s[qt][3]));
        p[qt] = __builtin_shufflevector(plo, phi, 0, 1, 2, 3);
      }
      f16x4 vv[4];
      vv[0] = __builtin_shufflevector(vB0, vB0, 0, 1, 2, 3);
      vv[1] = __builtin_shufflevector(vB0, vB0, 4, 5, 6, 7);
      vv[2] = __builtin_shufflevector(vB1, vB1, 0, 1, 2, 3);
      vv[3] = __builtin_shufflevector(vB1, vB1, 4, 5, 6, 7);
#pragma unroll
      for (int dt = 0; dt < 4; dt++)
#pragma unroll
        for (int qt = 0; qt < 4; qt++)
          o[qt][dt] = __builtin_amdgcn_mfma_f32_16x16x16f16(p[qt], vv[dt], o[qt][dt], 0, 0, 0);
#pragma unroll
      for (int qt = 0; qt < 4; qt++)
        lacc[qt] = __builtin_amdgcn_mfma_f32_16x16x16f16(p[qt], ones, lacc[qt], 0, 0, 0);
      vB0 = *(const f16x8*)(Vp + nk);
      vB1 = *(const f16x8*)(Vp + nk + 8);
    }
  }

  // lacc C-layout: lane holds q=quad*4+r (all cols equal) -> no shuffles
#pragma unroll
  for (int qt = 0; qt < 4; qt++) {
#pragma unroll
    for (int r = 0; r < 4; r++) {
      float inv = 1.0f / lacc[qt][r];
      int q = qb * 256 + wave * 64 + qt * 16 + quad * 4 + r;
#pragma unroll
      for (int dt = 0; dt < 4; dt++)
        out[((size_t)bb * NS + q) * ND + hh * 64 + dt * 16 + lr] = o[qt][dt][r] * inv;
    }
  }
}

extern "C" void kernel_launch(void* const* d_in, const int* in_sizes, int n_in,
                              void* d_out, int out_size, void* d_ws, size_t ws_size,
                              hipStream_t stream) {
  const float* X  = (const float*)d_in[0];
  const float* Wq = (const float*)d_in[1];
  const float* bq = (const float*)d_in[2];
  const float* Wk = (const float*)d_in[3];
  const float* bk = (const float*)d_in[4];
  const float* Wv = (const float*)d_in[5];
  const float* bv = (const float*)d_in[6];
  float* out = (float*)d_out;

  // ws: Xh 16MB | Wh 6MB | QF 16MB | KF 16MB | VF 16MB = 70MB
  f16* Xh = (f16*)d_ws;
  f16* Wh = (f16*)((char*)d_ws + (size_t)(16u << 20));
  f16* QF = (f16*)((char*)d_ws + (size_t)(22u << 20));
  f16* KF = (f16*)((char*)d_ws + (size_t)(38u << 20));
  f16* VF = (f16*)((char*)d_ws + (size_t)(54u << 20));

  cvt_all<<<11264, 256, 0, stream>>>(X, Wq, Wk, Wv, Xh, Wh);
  qkv_gemm<<<dim3(64, 24), 256, 0, stream>>>(Xh, Wh, bq, bk, bv, QF, KF, VF);
  attn_kernel<<<dim3(8, 64), 256, 0, stream>>>(QF, KF, VF, out);
}